// Round 13
// baseline (187.454 us; speedup 1.0000x reference)
//
#include <hip/hip_runtime.h>
#include <stdint.h>
#include <math.h>

#define B_ 16
#define NN 16384
#define C_ 90
#define KSEL 100
#define MAXD 100
#define MFLAT (C_ * KSEL)   // 9000
#define NPAIR 128
#define ZKEY 0x80000000u    // fkey(0.0f)

// ---------- helpers ----------

// monotonic float->uint32 key (order-preserving for all non-NaN floats)
__device__ __forceinline__ uint32_t fkey(float f) {
  uint32_t u = __float_as_uint(f);
  return (u & 0x80000000u) ? ~u : (u | 0x80000000u);
}
__device__ __forceinline__ float keyinv(uint32_t k) {
  uint32_t u = (k & 0x80000000u) ? (k & 0x7FFFFFFFu) : ~k;
  return __uint_as_float(u);
}

// block sum over 512 threads (8 waves)
__device__ __forceinline__ uint32_t blockSum512(uint32_t v, uint32_t* red, uint32_t* s_total) {
  int tid = threadIdx.x;
#pragma unroll
  for (int o = 32; o > 0; o >>= 1) v += __shfl_down(v, o, 64);
  if ((tid & 63) == 0) red[tid >> 6] = v;
  __syncthreads();
  if (tid == 0) {
    uint32_t s = 0;
#pragma unroll
    for (int i = 0; i < 8; ++i) s += red[i];
    *s_total = s;
  }
  __syncthreads();
  return *s_total;
}

// ---------- kernel B: transpose [B,N,C] -> [B,C,N] uint16 keys of RAW logits ----------
// k16 = fkey(logit) >> 16 is order-preserving; sigmoid applied later only to winners.
__global__ __launch_bounds__(256) void transpose_key16_kernel(const float* __restrict__ logits,
                                                              uint16_t* __restrict__ keys16T) {
  __shared__ uint32_t tile[128 * 91];   // 128 n-rows x 90 classes (full fkey32), padded
  int b = blockIdx.y;
  int n0 = blockIdx.x * 128;
  const float4* src4 = reinterpret_cast<const float4*>(logits + ((size_t)b * NN + n0) * C_);
  for (int p = threadIdx.x; p < 2880; p += 256) {   // 128*90/4
    float4 v = src4[p];
    int e = p * 4;
    float vv[4] = {v.x, v.y, v.z, v.w};
#pragma unroll
    for (int j = 0; j < 4; ++j) {
      int ee = e + j;
      tile[(ee / C_) * 91 + (ee % C_)] = fkey(vv[j]);
    }
  }
  __syncthreads();
  uint16_t* dstb = keys16T + (size_t)b * C_ * NN + n0;
  for (int q = threadIdx.x; q < C_ * 16; q += 256) {   // 90 classes x 16 uint4 (8 u16 each)
    int c = q >> 4, g = q & 15;
    int nn2 = g * 8;
    uint4 o;
    o.x = (tile[(nn2 + 0) * 91 + c] >> 16) | (tile[(nn2 + 1) * 91 + c] & 0xFFFF0000u);
    o.y = (tile[(nn2 + 2) * 91 + c] >> 16) | (tile[(nn2 + 3) * 91 + c] & 0xFFFF0000u);
    o.z = (tile[(nn2 + 4) * 91 + c] >> 16) | (tile[(nn2 + 5) * 91 + c] & 0xFFFF0000u);
    o.w = (tile[(nn2 + 6) * 91 + c] >> 16) | (tile[(nn2 + 7) * 91 + c] & 0xFFFF0000u);
    reinterpret_cast<uint4*>(dstb + (size_t)c * NN)[g] = o;
  }
}

// ---------- kernel C (FUSED): per-(b,c) radix-select + rescore + rank + NMS ----------
// Round-12 lesson: __launch_bounds__(512,8) forced VGPR<=32 -> keyw[16] spilled
// to scratch (WRITE 9.5MB vs 2.9MB real output, FETCH 42 vs 23MB). (512,4) caps
// at 64 VGPR -- round 6's identical select phase used 40 there, spill-free.
// Level-0 histogram striped into 2 wave-parity copies (halves the 3.9M LDS
// same-bin conflict cycles from clustered sigmoid keys).
template <int TR>
__global__ __launch_bounds__(512, 4) void select_nms_kernel(
    const uint16_t* __restrict__ keys16T,  // [B][C][N] (TR=1)
    const float* __restrict__ logits,      // [B][N][C] raw
    const float* __restrict__ enc,         // [B][N][4]
    const float* __restrict__ anchors,     // [N][4]
    float* __restrict__ candBox,           // [B][C][K][4]
    float* __restrict__ candScore) {       // [B][C][K]
  __shared__ uint32_t hist[4096];             // 2 wave-parity copies x 2048 bins
  __shared__ uint32_t sc[512];
  __shared__ uint32_t ws8[64];
  __shared__ int s_bsel;
  __shared__ uint32_t s_Sincl, s_Sexcl;
  __shared__ uint32_t red[8];
  __shared__ uint32_t s_total;
  __shared__ uint32_t s_cnt;
  __shared__ uint32_t s_cand[NPAIR];          // collected (k16<<16)|idx
  __shared__ unsigned long long ck[NPAIR];    // slot-indexed exact keys
  __shared__ float p_box[NPAIR][4];           // slot order, float4-aligned
  __shared__ float p_area[NPAIR];
  __shared__ uint32_t s_sl[NPAIR];            // rank -> slot | (ok<<8)
  __shared__ unsigned long long M[NPAIR][2];  // slot-space IoU rows
  __shared__ unsigned long long s_keepw[2];

  const int c = blockIdx.x, b = blockIdx.y;
  const int tid = threadIdx.x;
  const int bc = b * C_ + c;
  const uint32_t hoff = ((uint32_t)(tid >> 6) & 1u) << 11;   // wave-parity stripe

  // ---- load 32 u16 keys/thread (16 packed words) ----
  uint32_t keyw[16];
  if (TR) {
    const uint4* src4 = reinterpret_cast<const uint4*>(keys16T + ((size_t)b * C_ + c) * NN);
#pragma unroll
    for (int q = 0; q < 4; ++q) {
      uint4 kv = src4[q * 512 + tid];
      keyw[4 * q + 0] = kv.x; keyw[4 * q + 1] = kv.y;
      keyw[4 * q + 2] = kv.z; keyw[4 * q + 3] = kv.w;
    }
  } else {
    const float* src = logits + (size_t)b * NN * C_ + c;
#pragma unroll
    for (int m = 0; m < 16; ++m) {
      uint32_t i0 = (uint32_t)((((m >> 2) * 512 + tid) * 8) + ((m & 3) * 2));
      uint32_t klo = fkey(src[(size_t)i0 * C_]) >> 16;
      uint32_t khi = fkey(src[(size_t)(i0 + 1) * C_]) >> 16;
      keyw[m] = klo | (khi << 16);
    }
  }

  // ---- level 0: striped 2048-bin histogram over bits 15:5 ----
  reinterpret_cast<uint4*>(hist)[tid] = make_uint4(0u, 0u, 0u, 0u);         // 2048 words
  reinterpret_cast<uint4*>(hist)[512 + tid] = make_uint4(0u, 0u, 0u, 0u);   // 2048 more
  __syncthreads();
#pragma unroll
  for (int m = 0; m < 16; ++m) {
    uint32_t w = keyw[m];
    atomicAdd(&hist[hoff + ((w & 0xFFFFu) >> 5)], 1u);
    atomicAdd(&hist[hoff + (w >> 21)], 1u);   // (w>>16)>>5
  }
  __syncthreads();

  uint32_t m_above = 0;
  uint32_t need = 100u;
  uint32_t cut16 = 0;
  int found = 0;
  int tiepath = 0;
  uint32_t V16 = 0, Texact = NN - 1;

  {
    uint32_t h0 = hist[4 * tid] + hist[2048 + 4 * tid];
    uint32_t h1 = hist[4 * tid + 1] + hist[2048 + 4 * tid + 1];
    uint32_t h2 = hist[4 * tid + 2] + hist[2048 + 4 * tid + 2];
    uint32_t h3 = hist[4 * tid + 3] + hist[2048 + 4 * tid + 3];
    sc[tid] = h0 + h1 + h2 + h3;
    if (tid == 0) s_bsel = -1;
    __syncthreads();
    if (tid < 64) {   // wave 0: inclusive suffix over 8-chunk groups
      uint32_t w = 0;
      int base = tid * 8;
#pragma unroll
      for (int i = 0; i < 8; ++i) w += sc[base + i];
#pragma unroll
      for (int off = 1; off < 64; off <<= 1) {
        uint32_t v = __shfl_down(w, off, 64);
        if (tid + off < 64) w += v;
      }
      ws8[tid] = w;
    }
    __syncthreads();
    {
      int g = tid >> 3;
      uint32_t above = (g < 63) ? ws8[g + 1] : 0u;
      for (int j = (g << 3) + 7; j > tid; --j) above += sc[j];
      uint32_t run = above;
      int best = -1;
      uint32_t bi = 0, be = 0;
      uint32_t hh[4] = {h0, h1, h2, h3};
#pragma unroll
      for (int p = 3; p >= 0; --p) {
        uint32_t h = hh[p];
        run += h;
        if (best < 0 && run >= need) { best = 4 * tid + p; bi = run; be = run - h; }
      }
      if (best >= 0) atomicMax(&s_bsel, best);
      __syncthreads();
      if (best >= 0 && best == s_bsel) { s_Sincl = bi; s_Sexcl = be; }
    }
    __syncthreads();

    uint32_t bsel = (uint32_t)s_bsel;
    uint32_t Sincl = s_Sincl, Sexcl = s_Sexcl;
    if (Sincl <= (uint32_t)NPAIR) {
      cut16 = bsel << 5;
      found = 1;
    } else {
      m_above = Sexcl;
      need = 100u - m_above;
      // ---- level 1: 32 bins (bits 4:0) within prefix bsel ----
      __syncthreads();
      if (tid < 8) reinterpret_cast<uint4*>(hist)[tid] = make_uint4(0u, 0u, 0u, 0u);
      __syncthreads();
#pragma unroll
      for (int m = 0; m < 16; ++m) {
        uint32_t w = keyw[m];
        uint32_t klo = w & 0xFFFFu, khi = w >> 16;
        if ((klo >> 5) == bsel) atomicAdd(&hist[klo & 31u], 1u);
        if ((khi >> 5) == bsel) atomicAdd(&hist[khi & 31u], 1u);
      }
      __syncthreads();
      // redundant all-thread suffix scan over 32 bins (uniform result)
      uint32_t run = 0;
      int b1 = -1;
      uint32_t Si = 0, Se = 0;
      for (int p = 31; p >= 0; --p) {
        uint32_t h = hist[p];
        run += h;
        if (b1 < 0 && run >= need) { b1 = p; Si = run; Se = run - h; }
      }
      uint32_t cutv = (bsel << 5) | (uint32_t)b1;
      if (m_above + Si <= (uint32_t)NPAIR) {
        cut16 = cutv;
        found = 1;
      } else {
        // >128 exact 16-bit ties at the cut (essentially impossible on real data)
        tiepath = 1;
        V16 = cutv;
        m_above += Se;
        uint32_t r = 100u - m_above;
        uint32_t lo2 = 0, hi2 = NN - 1;
        while (lo2 < hi2) {
          uint32_t mid2 = lo2 + ((hi2 - lo2) >> 1);
          uint32_t cnt2 = 0;
#pragma unroll
          for (int m = 0; m < 16; ++m) {
            uint32_t w = keyw[m];
            uint32_t i0 = (uint32_t)((((m >> 2) * 512 + tid) * 8) + ((m & 3) * 2));
            cnt2 += ((w & 0xFFFFu) == V16 && i0 <= mid2) ? 1u : 0u;
            cnt2 += ((w >> 16) == V16 && (i0 + 1) <= mid2) ? 1u : 0u;
          }
          uint32_t tot = blockSum512(cnt2, red, &s_total);
          if (tot >= r) hi2 = mid2; else lo2 = mid2 + 1;
        }
        Texact = lo2;
      }
    }
  }

  // ---- collect candidates (100..128) into LDS, unsorted, packed u32 ----
  if (tid == 0) s_cnt = 0;
  __syncthreads();
#pragma unroll
  for (int m = 0; m < 16; ++m) {
    uint32_t w = keyw[m];
    uint32_t i0 = (uint32_t)((((m >> 2) * 512 + tid) * 8) + ((m & 3) * 2));
    uint32_t klo = w & 0xFFFFu, khi = w >> 16;
    bool t0 = tiepath ? (klo > V16 || (klo == V16 && i0 <= Texact)) : (klo >= cut16);
    bool t1 = tiepath ? (khi > V16 || (khi == V16 && (i0 + 1) <= Texact)) : (khi >= cut16);
    if (t0) {
      uint32_t p = atomicAdd(&s_cnt, 1u);
      if (p < (uint32_t)NPAIR) s_cand[p] = (klo << 16) | i0;
    }
    if (t1) {
      uint32_t p = atomicAdd(&s_cnt, 1u);
      if (p < (uint32_t)NPAIR) s_cand[p] = (khi << 16) | (i0 + 1);
    }
  }
  __syncthreads();
  const uint32_t cnt = (s_cnt > (uint32_t)NPAIR) ? (uint32_t)NPAIR : s_cnt;

  // ==== NMS stage (round-11 rank version, verbatim; threads 0-255 active) ====

  // ---- phase 1: gather + decode ----
  unsigned long long myKey = 0ull;
  bool myOk = false;
  float ry1 = 0, rx1 = 0, ry2 = 0, rx2 = 0, rar = 0;

  if (tid < NPAIR) {
    int s = tid;
    uint32_t v = (s < (int)cnt) ? s_cand[s] : 0u;
    int n = (s < (int)cnt) ? (int)(v & 0x3FFFu) : 0;
    float x = logits[((size_t)b * NN + n) * C_ + c];
    float sv = 1.0f / (1.0f + expf(-x));
    myOk = (sv > 0.05f);
    myKey = (s < (int)cnt)
        ? (((unsigned long long)fkey(sv) << 32) |
           (unsigned long long)((((uint32_t)(NN - 1 - n)) << 7) | (uint32_t)s))
        : (unsigned long long)s;
    ck[s] = myKey;
  } else if (tid < 2 * NPAIR) {
    int s = tid - NPAIR;
    uint32_t v = (s < (int)cnt) ? s_cand[s] : 0u;
    int n = (s < (int)cnt) ? (int)(v & 0x3FFFu) : 0;
    float4 e = reinterpret_cast<const float4*>(enc)[(size_t)b * NN + n];
    float4 a = reinterpret_cast<const float4*>(anchors)[n];
    float ha = a.z - a.x, wa = a.w - a.y;
    float cya = (a.x + a.z) * 0.5f, cxa = (a.y + a.w) * 0.5f;
    float cy = (e.x / 10.0f) * ha + cya;
    float cx = (e.y / 10.0f) * wa + cxa;
    float h = expf(e.z / 5.0f) * ha;
    float w = expf(e.w / 5.0f) * wa;
    ry1 = fminf(fmaxf(cy - h * 0.5f, 0.0f), 1.0f);
    rx1 = fminf(fmaxf(cx - w * 0.5f, 0.0f), 1.0f);
    ry2 = fminf(fmaxf(cy + h * 0.5f, 0.0f), 1.0f);
    rx2 = fminf(fmaxf(cx + w * 0.5f, 0.0f), 1.0f);
    rar = fmaxf(ry2 - ry1, 0.0f) * fmaxf(rx2 - rx1, 0.0f);
    float4* pb = reinterpret_cast<float4*>(p_box[s]);
    *pb = make_float4(ry1, rx1, ry2, rx2);
    p_area[s] = rar;
  }
  __syncthreads();

  // ---- phase 2: rank via broadcast compare-count || IoU bit-matrix ----
  if (tid < NPAIR) {
    uint32_t rank = 0;
#pragma unroll 8
    for (int j = 0; j < NPAIR; ++j) rank += (ck[j] > myKey) ? 1u : 0u;
    s_sl[rank] = (uint32_t)tid | (myOk ? 256u : 0u);
  } else if (tid < 2 * NPAIR) {
    int s = tid - NPAIR;
    unsigned long long m0 = 0ull, m1 = 0ull;
#pragma unroll 4
    for (int q = 0; q < NPAIR; ++q) {
      float4 bq = *reinterpret_cast<const float4*>(p_box[q]);
      float aq = p_area[q];
      float ta = fmaxf(fminf(bq.z, ry2) - fmaxf(bq.x, ry1), 0.0f) *
                 fmaxf(fminf(bq.w, rx2) - fmaxf(bq.y, rx1), 0.0f);
      float un = fmaxf(aq + rar - ta, 1e-8f);
      bool hit = (ta / un >= 0.5f);
      if (q < 64) m0 |= (unsigned long long)hit << q;
      else        m1 |= (unsigned long long)hit << (q - 64);
    }
    M[s][0] = m0; M[s][1] = m1;
  }
  __syncthreads();

  // ---- phase 3: greedy scan over ranks (wave 0; ALU-only carried chain) ----
  if (tid < 64) {
    unsigned long long supp0 = 0, supp1 = 0, k0 = 0, k1 = 0;
#pragma unroll 4
    for (int j = 0; j < KSEL; ++j) {
      uint32_t e = s_sl[j];
      int sl = (int)(e & 127u);
      unsigned long long r0 = M[sl][0], r1 = M[sl][1];
      bool suppd = (sl < 64) ? ((supp0 >> sl) & 1ull) : ((supp1 >> (sl - 64)) & 1ull);
      bool pass = (e & 256u) && !suppd;
      if (pass) {
        supp0 |= r0; supp1 |= r1;
        if (j < 64) k0 |= 1ull << j; else k1 |= 1ull << (j - 64);
      }
    }
    if (tid == 0) { s_keepw[0] = k0; s_keepw[1] = k1; }
  }
  __syncthreads();

  // ---- phase 4: output by rank (cnt >= 100 always) ----
  if (tid < KSEL) {
    int slot = (int)(s_sl[tid] & 127u);
    unsigned long long keyv = ck[slot];
    bool kept = (tid < 64) ? ((s_keepw[0] >> tid) & 1ull)
                           : ((s_keepw[1] >> (tid - 64)) & 1ull);
    size_t base = (size_t)bc * KSEL + tid;
    candScore[base] = kept ? keyinv((uint32_t)(keyv >> 32)) : 0.0f;
    float* cb = candBox + base * 4;
    cb[0] = p_box[slot][0]; cb[1] = p_box[slot][1];
    cb[2] = p_box[slot][2]; cb[3] = p_box[slot][3];
  }
}

// ---------- kernel D: per-image final top-100, LDS-resident keys ----------
#define FT_NT 512
#define FT_SLOTS 18   // 512*18 = 9216 >= 9000
#define FT_NW 8       // 8 waves, wave-private histogram copies
__global__ __launch_bounds__(FT_NT) void final_topk_kernel(
    const float* __restrict__ candScore,  // [B][C*K]
    const float* __restrict__ candBox,    // [B][C*K][4]
    float* __restrict__ out) {            // [B][MAXD][6]
  __shared__ uint32_t skey[FT_NT * FT_SLOTS];   // 36,864 B: all 9216 keys
  __shared__ uint32_t hist[FT_NW * 2048];       // 65,536 B: per-wave histograms
  __shared__ uint32_t sc[512];
  __shared__ uint32_t ws8[64];
  __shared__ int s_bsel;
  __shared__ uint32_t s_Sincl, s_Sexcl;
  __shared__ uint32_t red[8];
  __shared__ uint32_t s_total;
  __shared__ uint32_t s_cnt;
  __shared__ unsigned long long ck[128];

  int b = blockIdx.x, tid = threadIdx.x;
  const int wid = tid >> 6;
  const float* src = candScore + (size_t)b * MFLAT;

  // ---- load keys into LDS (coalesced), count strictly-positive scores ----
  uint32_t nzc = 0;
  for (int q = 0; q < FT_SLOTS; ++q) {
    int idx = q * FT_NT + tid;
    uint32_t k = (idx < MFLAT) ? fkey(src[idx]) : 0u;   // pad key 0 < any real key
    skey[idx] = k;
    nzc += (k > ZKEY) ? 1u : 0u;
  }
  __syncthreads();
  uint32_t nz = blockSum512(nzc, red, &s_total);

  uint32_t cutHi = 0, m_above = 0, cut32 = 0;
  int found = 0, tiepath = 0;
  uint32_t V32 = 0, Texact = (uint32_t)(MFLAT - 1);
  uint32_t tie_r = 0;

  if (nz < 100u) {
    tiepath = 1;
    V32 = ZKEY;
    tie_r = 100u - nz;
  } else {
    for (int lvl = 0; lvl < 3; ++lvl) {
      const int shiftLo = (lvl == 0) ? 21 : (lvl == 1) ? 10 : 0;
      const uint32_t mask = (lvl == 2) ? 0x3FFu : 0x7FFu;
      const int nbits = (lvl == 2) ? 10 : 11;

      for (int i = tid; i < FT_NW * 512; i += FT_NT)   // 16384 words as uint4
        reinterpret_cast<uint4*>(hist)[i] = make_uint4(0u, 0u, 0u, 0u);
      __syncthreads();
      uint32_t* myh = hist + wid * 2048;
      for (int q = 0; q < FT_SLOTS; ++q) {
        uint32_t k = skey[q * FT_NT + tid];
        bool in = (k > ZKEY) && ((lvl == 0) ? true : ((k >> (shiftLo + nbits)) == cutHi));
        if (in) atomicAdd(&myh[(k >> shiftLo) & mask], 1u);
      }
      __syncthreads();

      const uint32_t need = 100u - m_above;

      uint32_t h0 = 0, h1 = 0, h2 = 0, h3 = 0;
#pragma unroll
      for (int w = 0; w < FT_NW; ++w) {
        uint4 a = *reinterpret_cast<const uint4*>(hist + w * 2048 + 4 * tid);
        h0 += a.x; h1 += a.y; h2 += a.z; h3 += a.w;
      }
      sc[tid] = h0 + h1 + h2 + h3;
      if (tid == 0) s_bsel = -1;
      __syncthreads();
      if (tid < 64) {
        uint32_t w = 0;
        int base = tid * 8;
#pragma unroll
        for (int i = 0; i < 8; ++i) w += sc[base + i];
#pragma unroll
        for (int off = 1; off < 64; off <<= 1) {
          uint32_t v = __shfl_down(w, off, 64);
          if (tid + off < 64) w += v;
        }
        ws8[tid] = w;
      }
      __syncthreads();
      {
        int g = tid >> 3;
        uint32_t above = (g < 63) ? ws8[g + 1] : 0u;
        for (int j = (g << 3) + 7; j > tid; --j) above += sc[j];
        uint32_t run = above;
        int best = -1;
        uint32_t bi = 0, be = 0;
        uint32_t hh[4] = {h0, h1, h2, h3};
#pragma unroll
        for (int p = 3; p >= 0; --p) {
          uint32_t h = hh[p];
          run += h;
          if (best < 0 && run >= need) { best = 4 * tid + p; bi = run; be = run - h; }
        }
        if (best >= 0) atomicMax(&s_bsel, best);
        __syncthreads();
        if (best >= 0 && best == s_bsel) { s_Sincl = bi; s_Sexcl = be; }
      }
      __syncthreads();

      uint32_t bsel = (uint32_t)s_bsel;
      cutHi = (cutHi << nbits) | bsel;
      if (m_above + s_Sincl <= 128u) {
        cut32 = cutHi << shiftLo;
        found = 1;
        break;
      }
      m_above += s_Sexcl;
      __syncthreads();
    }

    if (!found) {
      tiepath = 1;
      V32 = cutHi;
      tie_r = 100u - m_above;
    }
  }

  if (tiepath) {
    uint32_t lo2 = 0, hi2 = (uint32_t)(MFLAT - 1);
    while (lo2 < hi2) {
      uint32_t mid2 = lo2 + ((hi2 - lo2) >> 1);
      uint32_t cnt = 0;
      for (int q = 0; q < FT_SLOTS; ++q) {
        uint32_t idx = (uint32_t)(q * FT_NT + tid);
        cnt += (skey[idx] == V32 && idx <= mid2) ? 1u : 0u;
      }
      uint32_t tot = blockSum512(cnt, red, &s_total);
      if (tot >= tie_r) hi2 = mid2; else lo2 = mid2 + 1;
    }
    Texact = lo2;
  }

  // collect candidates (100..128), pad, sort
  if (tid == 0) s_cnt = 0;
  __syncthreads();
  for (int q = 0; q < FT_SLOTS; ++q) {
    uint32_t idx = (uint32_t)(q * FT_NT + tid);
    uint32_t k = skey[idx];
    bool take = tiepath ? (k > V32 || (k == V32 && idx <= Texact))
                        : (k > ZKEY && k >= cut32);
    if (take) {
      uint32_t p = atomicAdd(&s_cnt, 1u);
      if (p < 128u)
        ck[p] = ((unsigned long long)k << 32) | (unsigned long long)(~idx);
    }
  }
  __syncthreads();
  if (tid < 128 && (uint32_t)tid >= s_cnt) ck[tid] = 0ull;
  __syncthreads();

  // bitonic sort 128 descending by (key, ~idx)
  for (int kk = 2; kk <= 128; kk <<= 1) {
    for (int j = kk >> 1; j > 0; j >>= 1) {
      if (tid < 128) {
        int ixj = tid ^ j;
        if (ixj > tid) {
          unsigned long long a = ck[tid], bb = ck[ixj];
          if ((a < bb) == ((tid & kk) == 0)) { ck[tid] = bb; ck[ixj] = a; }
        }
      }
      __syncthreads();
    }
  }

  if (tid < MAXD) {
    unsigned long long keyv = ck[tid];
    int f = (int)(~(uint32_t)(keyv & 0xFFFFFFFFull));   // flat idx = c*K + k
    int c = f / KSEL;
    float sc2 = keyinv((uint32_t)(keyv >> 32));
    const float* cb = candBox + ((size_t)b * MFLAT + f) * 4;
    float* o = out + ((size_t)b * MAXD + tid) * 6;
    o[0] = cb[0]; o[1] = cb[1]; o[2] = cb[2]; o[3] = cb[3];
    o[4] = (float)c; o[5] = sc2;
  }
}

// ---------- host ----------
extern "C" void kernel_launch(void* const* d_in, const int* in_sizes, int n_in,
                              void* d_out, int out_size, void* d_ws, size_t ws_size,
                              hipStream_t stream) {
  const float* enc = (const float*)d_in[0];      // [B,N,4]
  const float* logits = (const float*)d_in[1];   // [B,N,C]
  const float* anchors = (const float*)d_in[2];  // [N,4]
  float* out = (float*)d_out;                    // [B,100,6]
  char* ws = (char*)d_ws;

  size_t off = 0;
  float* candBox = (float*)(ws + off);   off += (size_t)B_ * C_ * KSEL * 4 * sizeof(float); // 2.30 MB
  float* candScore = (float*)(ws + off); off += (size_t)B_ * C_ * KSEL * sizeof(float);     // 0.58 MB
  off = (off + 255) & ~(size_t)255;
  uint16_t* keys16T = (uint16_t*)(ws + off);
  size_t needT = off + (size_t)B_ * C_ * NN * sizeof(uint16_t);                             // +47.2 MB
  int transposed = (ws_size >= needT) ? 1 : 0;

  if (transposed) {
    transpose_key16_kernel<<<dim3(NN / 128, B_), 256, 0, stream>>>(logits, keys16T);
    select_nms_kernel<1><<<dim3(C_, B_), 512, 0, stream>>>(keys16T, logits, enc, anchors,
                                                           candBox, candScore);
  } else {
    select_nms_kernel<0><<<dim3(C_, B_), 512, 0, stream>>>(keys16T, logits, enc, anchors,
                                                           candBox, candScore);
  }

  final_topk_kernel<<<B_, FT_NT, 0, stream>>>(candScore, candBox, out);
}

// Round 14
// 134.464 us; speedup vs baseline: 1.3941x; 1.3941x over previous
//
#include <hip/hip_runtime.h>
#include <stdint.h>
#include <math.h>

#define B_ 16
#define NN 16384
#define C_ 90
#define KSEL 100
#define MAXD 100
#define MFLAT (C_ * KSEL)   // 9000
#define NPAIR 128
#define ZKEY 0x80000000u    // fkey(0.0f)

// ---------- helpers ----------

// monotonic float->uint32 key (order-preserving for all non-NaN floats)
__device__ __forceinline__ uint32_t fkey(float f) {
  uint32_t u = __float_as_uint(f);
  return (u & 0x80000000u) ? ~u : (u | 0x80000000u);
}
__device__ __forceinline__ float keyinv(uint32_t k) {
  uint32_t u = (k & 0x80000000u) ? (k & 0x7FFFFFFFu) : ~k;
  return __uint_as_float(u);
}

// block sum over 512 threads (8 waves)
__device__ __forceinline__ uint32_t blockSum512(uint32_t v, uint32_t* red, uint32_t* s_total) {
  int tid = threadIdx.x;
#pragma unroll
  for (int o = 32; o > 0; o >>= 1) v += __shfl_down(v, o, 64);
  if ((tid & 63) == 0) red[tid >> 6] = v;
  __syncthreads();
  if (tid == 0) {
    uint32_t s = 0;
#pragma unroll
    for (int i = 0; i < 8; ++i) s += red[i];
    *s_total = s;
  }
  __syncthreads();
  return *s_total;
}

// ---------- kernel B: transpose [B,N,C] -> [B,C,N] uint16 keys of RAW logits ----------
// k16 = fkey(logit) >> 16 is order-preserving; sigmoid applied later only to winners.
__global__ __launch_bounds__(256) void transpose_key16_kernel(const float* __restrict__ logits,
                                                              uint16_t* __restrict__ keys16T) {
  __shared__ uint32_t tile[128 * 91];   // 128 n-rows x 90 classes (full fkey32), padded
  int b = blockIdx.y;
  int n0 = blockIdx.x * 128;
  const float4* src4 = reinterpret_cast<const float4*>(logits + ((size_t)b * NN + n0) * C_);
  for (int p = threadIdx.x; p < 2880; p += 256) {   // 128*90/4
    float4 v = src4[p];
    int e = p * 4;
    float vv[4] = {v.x, v.y, v.z, v.w};
#pragma unroll
    for (int j = 0; j < 4; ++j) {
      int ee = e + j;
      tile[(ee / C_) * 91 + (ee % C_)] = fkey(vv[j]);
    }
  }
  __syncthreads();
  uint16_t* dstb = keys16T + (size_t)b * C_ * NN + n0;
  for (int q = threadIdx.x; q < C_ * 16; q += 256) {   // 90 classes x 16 uint4 (8 u16 each)
    int c = q >> 4, g = q & 15;
    int nn2 = g * 8;
    uint4 o;
    o.x = (tile[(nn2 + 0) * 91 + c] >> 16) | (tile[(nn2 + 1) * 91 + c] & 0xFFFF0000u);
    o.y = (tile[(nn2 + 2) * 91 + c] >> 16) | (tile[(nn2 + 3) * 91 + c] & 0xFFFF0000u);
    o.z = (tile[(nn2 + 4) * 91 + c] >> 16) | (tile[(nn2 + 5) * 91 + c] & 0xFFFF0000u);
    o.w = (tile[(nn2 + 6) * 91 + c] >> 16) | (tile[(nn2 + 7) * 91 + c] & 0xFFFF0000u);
    reinterpret_cast<uint4*>(dstb + (size_t)c * NN)[g] = o;
  }
}

// ---------- kernel C1: per-(b,c) radix-select top-100 on 16-bit keys ----------
template <int TR>
__global__ __launch_bounds__(512, 8) void select_kernel(
    const uint16_t* __restrict__ keys16T,  // [B][C][N] (TR=1)
    const float* __restrict__ logits,      // [B][N][C] raw (TR=0 fallback)
    uint32_t* __restrict__ candPacked,     // [B*C][NPAIR]  (k16<<16)|idx
    uint32_t* __restrict__ candCount) {    // [B*C]
  __shared__ uint32_t hist[2048];
  __shared__ uint32_t sc[512];
  __shared__ uint32_t ws8[64];
  __shared__ int s_bsel;
  __shared__ uint32_t s_Sincl, s_Sexcl;
  __shared__ uint32_t red[8];
  __shared__ uint32_t s_total;
  __shared__ uint32_t s_cnt;

  const int c = blockIdx.x, b = blockIdx.y;
  const int tid = threadIdx.x;

  // ---- load 32 u16 keys/thread (16 packed words) ----
  uint32_t keyw[16];
  if (TR) {
    const uint4* src4 = reinterpret_cast<const uint4*>(keys16T + ((size_t)b * C_ + c) * NN);
#pragma unroll
    for (int q = 0; q < 4; ++q) {
      uint4 kv = src4[q * 512 + tid];
      keyw[4 * q + 0] = kv.x; keyw[4 * q + 1] = kv.y;
      keyw[4 * q + 2] = kv.z; keyw[4 * q + 3] = kv.w;
    }
  } else {
    const float* src = logits + (size_t)b * NN * C_ + c;
#pragma unroll
    for (int m = 0; m < 16; ++m) {
      uint32_t i0 = (uint32_t)((((m >> 2) * 512 + tid) * 8) + ((m & 3) * 2));
      uint32_t klo = fkey(src[(size_t)i0 * C_]) >> 16;
      uint32_t khi = fkey(src[(size_t)(i0 + 1) * C_]) >> 16;
      keyw[m] = klo | (khi << 16);
    }
  }

  // ---- level 0: 2048-bin histogram over bits 15:5 ----
  reinterpret_cast<uint4*>(hist)[tid] = make_uint4(0u, 0u, 0u, 0u);   // 2048 words
  __syncthreads();
#pragma unroll
  for (int m = 0; m < 16; ++m) {
    uint32_t w = keyw[m];
    atomicAdd(&hist[(w & 0xFFFFu) >> 5], 1u);
    atomicAdd(&hist[w >> 21], 1u);   // (w>>16)>>5
  }
  __syncthreads();

  uint32_t m_above = 0;
  uint32_t need = 100u;
  uint32_t cut16 = 0;
  int found = 0;
  int tiepath = 0;
  uint32_t V16 = 0, Texact = NN - 1;

  {
    uint32_t h0 = hist[4 * tid], h1 = hist[4 * tid + 1];
    uint32_t h2 = hist[4 * tid + 2], h3 = hist[4 * tid + 3];
    sc[tid] = h0 + h1 + h2 + h3;
    if (tid == 0) s_bsel = -1;
    __syncthreads();
    if (tid < 64) {   // wave 0: inclusive suffix over 8-chunk groups
      uint32_t w = 0;
      int base = tid * 8;
#pragma unroll
      for (int i = 0; i < 8; ++i) w += sc[base + i];
#pragma unroll
      for (int off = 1; off < 64; off <<= 1) {
        uint32_t v = __shfl_down(w, off, 64);
        if (tid + off < 64) w += v;
      }
      ws8[tid] = w;
    }
    __syncthreads();
    {
      int g = tid >> 3;
      uint32_t above = (g < 63) ? ws8[g + 1] : 0u;
      for (int j = (g << 3) + 7; j > tid; --j) above += sc[j];
      uint32_t run = above;
      int best = -1;
      uint32_t bi = 0, be = 0;
      uint32_t hh[4] = {h0, h1, h2, h3};
#pragma unroll
      for (int p = 3; p >= 0; --p) {
        uint32_t h = hh[p];
        run += h;
        if (best < 0 && run >= need) { best = 4 * tid + p; bi = run; be = run - h; }
      }
      if (best >= 0) atomicMax(&s_bsel, best);
      __syncthreads();
      if (best >= 0 && best == s_bsel) { s_Sincl = bi; s_Sexcl = be; }
    }
    __syncthreads();

    uint32_t bsel = (uint32_t)s_bsel;
    uint32_t Sincl = s_Sincl, Sexcl = s_Sexcl;
    if (Sincl <= (uint32_t)NPAIR) {
      cut16 = bsel << 5;
      found = 1;
    } else {
      m_above = Sexcl;
      need = 100u - m_above;
      // ---- level 1: 32 bins (bits 4:0) within prefix bsel ----
      __syncthreads();
      if (tid < 8) reinterpret_cast<uint4*>(hist)[tid] = make_uint4(0u, 0u, 0u, 0u);
      __syncthreads();
#pragma unroll
      for (int m = 0; m < 16; ++m) {
        uint32_t w = keyw[m];
        uint32_t klo = w & 0xFFFFu, khi = w >> 16;
        if ((klo >> 5) == bsel) atomicAdd(&hist[klo & 31u], 1u);
        if ((khi >> 5) == bsel) atomicAdd(&hist[khi & 31u], 1u);
      }
      __syncthreads();
      // redundant all-thread suffix scan over 32 bins (uniform result)
      uint32_t run = 0;
      int b1 = -1;
      uint32_t Si = 0, Se = 0;
      for (int p = 31; p >= 0; --p) {
        uint32_t h = hist[p];
        run += h;
        if (b1 < 0 && run >= need) { b1 = p; Si = run; Se = run - h; }
      }
      uint32_t cutv = (bsel << 5) | (uint32_t)b1;
      if (m_above + Si <= (uint32_t)NPAIR) {
        cut16 = cutv;
        found = 1;
      } else {
        // >128 exact 16-bit ties at the cut (essentially impossible on real data)
        tiepath = 1;
        V16 = cutv;
        m_above += Se;
        uint32_t r = 100u - m_above;
        uint32_t lo2 = 0, hi2 = NN - 1;
        while (lo2 < hi2) {
          uint32_t mid2 = lo2 + ((hi2 - lo2) >> 1);
          uint32_t cnt = 0;
#pragma unroll
          for (int m = 0; m < 16; ++m) {
            uint32_t w = keyw[m];
            uint32_t i0 = (uint32_t)((((m >> 2) * 512 + tid) * 8) + ((m & 3) * 2));
            cnt += ((w & 0xFFFFu) == V16 && i0 <= mid2) ? 1u : 0u;
            cnt += ((w >> 16) == V16 && (i0 + 1) <= mid2) ? 1u : 0u;
          }
          uint32_t tot = blockSum512(cnt, red, &s_total);
          if (tot >= r) hi2 = mid2; else lo2 = mid2 + 1;
        }
        Texact = lo2;
      }
    }
  }

  // ---- collect candidates (100..128) to GLOBAL, unsorted, packed u32 ----
  if (tid == 0) s_cnt = 0;
  __syncthreads();
  uint32_t* outp = candPacked + (size_t)(b * C_ + c) * NPAIR;
#pragma unroll
  for (int m = 0; m < 16; ++m) {
    uint32_t w = keyw[m];
    uint32_t i0 = (uint32_t)((((m >> 2) * 512 + tid) * 8) + ((m & 3) * 2));
    uint32_t klo = w & 0xFFFFu, khi = w >> 16;
    bool t0 = tiepath ? (klo > V16 || (klo == V16 && i0 <= Texact)) : (klo >= cut16);
    bool t1 = tiepath ? (khi > V16 || (khi == V16 && (i0 + 1) <= Texact)) : (khi >= cut16);
    if (t0) {
      uint32_t p = atomicAdd(&s_cnt, 1u);
      if (p < (uint32_t)NPAIR) outp[p] = (klo << 16) | i0;
    }
    if (t1) {
      uint32_t p = atomicAdd(&s_cnt, 1u);
      if (p < (uint32_t)NPAIR) outp[p] = (khi << 16) | (i0 + 1);
    }
  }
  __syncthreads();
  if (tid == 0) candCount[b * C_ + c] = (s_cnt > (uint32_t)NPAIR) ? (uint32_t)NPAIR : s_cnt;
}

// ---------- kernel C2: per-(b,c) rescore + RANK-sort + NMS ----------
// Keys are unique (low bits embed slot), so rank_i = #{j: key_j > key_i} via 128
// broadcast LDS reads, zero barriers. 4 barrier phases total.
__global__ __launch_bounds__(256, 8) void sort_nms_kernel(
    const uint32_t* __restrict__ candPacked,  // [B*C][NPAIR]
    const uint32_t* __restrict__ candCount,   // [B*C]
    const float* __restrict__ logits,         // [B][N][C]
    const float* __restrict__ enc,            // [B][N][4]
    const float* __restrict__ anchors,        // [N][4]
    float* __restrict__ candBox,              // [B][C][K][4]
    float* __restrict__ candScore) {          // [B][C][K]
  __shared__ unsigned long long ck[NPAIR];    // slot-indexed keys
  __shared__ float p_box[NPAIR][4];           // slot order, float4-aligned
  __shared__ float p_area[NPAIR];
  __shared__ unsigned long long M[NPAIR][2];  // slot-space IoU rows (128 bits)
  __shared__ uint32_t s_sl[NPAIR];            // rank -> slot | (ok<<8)
  __shared__ unsigned long long s_keepw[2];

  const int c = blockIdx.x, b = blockIdx.y;
  const int tid = threadIdx.x;
  const int bc = b * C_ + c;
  const uint32_t cnt = candCount[bc];

  // ---- phase 1: gather + decode (both roles issue gathers immediately) ----
  unsigned long long myKey = 0ull;
  bool myOk = false;
  float ry1 = 0, rx1 = 0, ry2 = 0, rx2 = 0, rar = 0;

  if (tid < NPAIR) {
    int s = tid;
    uint32_t v = candPacked[(size_t)bc * NPAIR + s];
    int n = (s < (int)cnt) ? (int)(v & 0x3FFFu) : 0;
    float x = logits[((size_t)b * NN + n) * C_ + c];
    float sv = 1.0f / (1.0f + expf(-x));
    myOk = (sv > 0.05f);
    myKey = (s < (int)cnt)
        ? (((unsigned long long)fkey(sv) << 32) |
           (unsigned long long)((((uint32_t)(NN - 1 - n)) << 7) | (uint32_t)s))
        : (unsigned long long)s;
    ck[s] = myKey;
  } else {
    int s = tid - NPAIR;
    uint32_t v = candPacked[(size_t)bc * NPAIR + s];
    int n = (s < (int)cnt) ? (int)(v & 0x3FFFu) : 0;
    float4 e = reinterpret_cast<const float4*>(enc)[(size_t)b * NN + n];
    float4 a = reinterpret_cast<const float4*>(anchors)[n];
    float ha = a.z - a.x, wa = a.w - a.y;
    float cya = (a.x + a.z) * 0.5f, cxa = (a.y + a.w) * 0.5f;
    float cy = (e.x / 10.0f) * ha + cya;
    float cx = (e.y / 10.0f) * wa + cxa;
    float h = expf(e.z / 5.0f) * ha;
    float w = expf(e.w / 5.0f) * wa;
    ry1 = fminf(fmaxf(cy - h * 0.5f, 0.0f), 1.0f);
    rx1 = fminf(fmaxf(cx - w * 0.5f, 0.0f), 1.0f);
    ry2 = fminf(fmaxf(cy + h * 0.5f, 0.0f), 1.0f);
    rx2 = fminf(fmaxf(cx + w * 0.5f, 0.0f), 1.0f);
    rar = fmaxf(ry2 - ry1, 0.0f) * fmaxf(rx2 - rx1, 0.0f);
    float4* pb = reinterpret_cast<float4*>(p_box[s]);
    *pb = make_float4(ry1, rx1, ry2, rx2);
    p_area[s] = rar;
  }
  __syncthreads();

  // ---- phase 2: rank via broadcast compare-count || IoU bit-matrix ----
  if (tid < NPAIR) {
    uint32_t rank = 0;
#pragma unroll 8
    for (int j = 0; j < NPAIR; ++j) rank += (ck[j] > myKey) ? 1u : 0u;
    s_sl[rank] = (uint32_t)tid | (myOk ? 256u : 0u);
  } else {
    int s = tid - NPAIR;
    unsigned long long m0 = 0ull, m1 = 0ull;
#pragma unroll 4
    for (int q = 0; q < NPAIR; ++q) {
      float4 bq = *reinterpret_cast<const float4*>(p_box[q]);
      float aq = p_area[q];
      float ta = fmaxf(fminf(bq.z, ry2) - fmaxf(bq.x, ry1), 0.0f) *
                 fmaxf(fminf(bq.w, rx2) - fmaxf(bq.y, rx1), 0.0f);
      float un = fmaxf(aq + rar - ta, 1e-8f);
      bool hit = (ta / un >= 0.5f);
      if (q < 64) m0 |= (unsigned long long)hit << q;
      else        m1 |= (unsigned long long)hit << (q - 64);
    }
    M[s][0] = m0; M[s][1] = m1;
  }
  __syncthreads();

  // ---- phase 3: greedy scan over ranks (wave 0; ALU-only carried chain) ----
  if (tid < 64) {
    unsigned long long supp0 = 0, supp1 = 0, k0 = 0, k1 = 0;
#pragma unroll 4
    for (int j = 0; j < KSEL; ++j) {
      uint32_t e = s_sl[j];
      int sl = (int)(e & 127u);
      unsigned long long r0 = M[sl][0], r1 = M[sl][1];
      bool suppd = (sl < 64) ? ((supp0 >> sl) & 1ull) : ((supp1 >> (sl - 64)) & 1ull);
      bool pass = (e & 256u) && !suppd;
      if (pass) {
        supp0 |= r0; supp1 |= r1;
        if (j < 64) k0 |= 1ull << j; else k1 |= 1ull << (j - 64);
      }
    }
    if (tid == 0) { s_keepw[0] = k0; s_keepw[1] = k1; }
  }
  __syncthreads();

  // ---- phase 4: output by rank (cnt >= 100 always) ----
  if (tid < KSEL) {
    int slot = (int)(s_sl[tid] & 127u);
    unsigned long long keyv = ck[slot];
    bool kept = (tid < 64) ? ((s_keepw[0] >> tid) & 1ull)
                           : ((s_keepw[1] >> (tid - 64)) & 1ull);
    size_t base = (size_t)bc * KSEL + tid;
    candScore[base] = kept ? keyinv((uint32_t)(keyv >> 32)) : 0.0f;
    float* cb = candBox + base * 4;
    cb[0] = p_box[slot][0]; cb[1] = p_box[slot][1];
    cb[2] = p_box[slot][2]; cb[3] = p_box[slot][3];
  }
}

// ---------- kernel D: per-image final top-100, LDS-resident keys ----------
#define FT_NT 512
#define FT_SLOTS 18   // 512*18 = 9216 >= 9000
#define FT_NW 8       // 8 waves, wave-private histogram copies
__global__ __launch_bounds__(FT_NT) void final_topk_kernel(
    const float* __restrict__ candScore,  // [B][C*K]
    const float* __restrict__ candBox,    // [B][C*K][4]
    float* __restrict__ out) {            // [B][MAXD][6]
  __shared__ uint32_t skey[FT_NT * FT_SLOTS];   // 36,864 B: all 9216 keys
  __shared__ uint32_t hist[FT_NW * 2048];       // 65,536 B: per-wave histograms
  __shared__ uint32_t sc[512];
  __shared__ uint32_t ws8[64];
  __shared__ int s_bsel;
  __shared__ uint32_t s_Sincl, s_Sexcl;
  __shared__ uint32_t red[8];
  __shared__ uint32_t s_total;
  __shared__ uint32_t s_cnt;
  __shared__ unsigned long long ck[128];

  int b = blockIdx.x, tid = threadIdx.x;
  const int wid = tid >> 6;
  const float* src = candScore + (size_t)b * MFLAT;

  // ---- load keys into LDS (coalesced), count strictly-positive scores ----
  uint32_t nzc = 0;
  for (int q = 0; q < FT_SLOTS; ++q) {
    int idx = q * FT_NT + tid;
    uint32_t k = (idx < MFLAT) ? fkey(src[idx]) : 0u;   // pad key 0 < any real key
    skey[idx] = k;
    nzc += (k > ZKEY) ? 1u : 0u;
  }
  __syncthreads();
  uint32_t nz = blockSum512(nzc, red, &s_total);

  uint32_t cutHi = 0, m_above = 0, cut32 = 0;
  int found = 0, tiepath = 0;
  uint32_t V32 = 0, Texact = (uint32_t)(MFLAT - 1);
  uint32_t tie_r = 0;

  if (nz < 100u) {
    tiepath = 1;
    V32 = ZKEY;
    tie_r = 100u - nz;
  } else {
    for (int lvl = 0; lvl < 3; ++lvl) {
      const int shiftLo = (lvl == 0) ? 21 : (lvl == 1) ? 10 : 0;
      const uint32_t mask = (lvl == 2) ? 0x3FFu : 0x7FFu;
      const int nbits = (lvl == 2) ? 10 : 11;

      for (int i = tid; i < FT_NW * 512; i += FT_NT)   // 16384 words as uint4
        reinterpret_cast<uint4*>(hist)[i] = make_uint4(0u, 0u, 0u, 0u);
      __syncthreads();
      uint32_t* myh = hist + wid * 2048;
      for (int q = 0; q < FT_SLOTS; ++q) {
        uint32_t k = skey[q * FT_NT + tid];
        bool in = (k > ZKEY) && ((lvl == 0) ? true : ((k >> (shiftLo + nbits)) == cutHi));
        if (in) atomicAdd(&myh[(k >> shiftLo) & mask], 1u);
      }
      __syncthreads();

      const uint32_t need = 100u - m_above;

      uint32_t h0 = 0, h1 = 0, h2 = 0, h3 = 0;
#pragma unroll
      for (int w = 0; w < FT_NW; ++w) {
        uint4 a = *reinterpret_cast<const uint4*>(hist + w * 2048 + 4 * tid);
        h0 += a.x; h1 += a.y; h2 += a.z; h3 += a.w;
      }
      sc[tid] = h0 + h1 + h2 + h3;
      if (tid == 0) s_bsel = -1;
      __syncthreads();
      if (tid < 64) {
        uint32_t w = 0;
        int base = tid * 8;
#pragma unroll
        for (int i = 0; i < 8; ++i) w += sc[base + i];
#pragma unroll
        for (int off = 1; off < 64; off <<= 1) {
          uint32_t v = __shfl_down(w, off, 64);
          if (tid + off < 64) w += v;
        }
        ws8[tid] = w;
      }
      __syncthreads();
      {
        int g = tid >> 3;
        uint32_t above = (g < 63) ? ws8[g + 1] : 0u;
        for (int j = (g << 3) + 7; j > tid; --j) above += sc[j];
        uint32_t run = above;
        int best = -1;
        uint32_t bi = 0, be = 0;
        uint32_t hh[4] = {h0, h1, h2, h3};
#pragma unroll
        for (int p = 3; p >= 0; --p) {
          uint32_t h = hh[p];
          run += h;
          if (best < 0 && run >= need) { best = 4 * tid + p; bi = run; be = run - h; }
        }
        if (best >= 0) atomicMax(&s_bsel, best);
        __syncthreads();
        if (best >= 0 && best == s_bsel) { s_Sincl = bi; s_Sexcl = be; }
      }
      __syncthreads();

      uint32_t bsel = (uint32_t)s_bsel;
      cutHi = (cutHi << nbits) | bsel;
      if (m_above + s_Sincl <= 128u) {
        cut32 = cutHi << shiftLo;
        found = 1;
        break;
      }
      m_above += s_Sexcl;
      __syncthreads();
    }

    if (!found) {
      tiepath = 1;
      V32 = cutHi;
      tie_r = 100u - m_above;
    }
  }

  if (tiepath) {
    uint32_t lo2 = 0, hi2 = (uint32_t)(MFLAT - 1);
    while (lo2 < hi2) {
      uint32_t mid2 = lo2 + ((hi2 - lo2) >> 1);
      uint32_t cnt = 0;
      for (int q = 0; q < FT_SLOTS; ++q) {
        uint32_t idx = (uint32_t)(q * FT_NT + tid);
        cnt += (skey[idx] == V32 && idx <= mid2) ? 1u : 0u;
      }
      uint32_t tot = blockSum512(cnt, red, &s_total);
      if (tot >= tie_r) hi2 = mid2; else lo2 = mid2 + 1;
    }
    Texact = lo2;
  }

  // collect candidates (100..128), pad, sort
  if (tid == 0) s_cnt = 0;
  __syncthreads();
  for (int q = 0; q < FT_SLOTS; ++q) {
    uint32_t idx = (uint32_t)(q * FT_NT + tid);
    uint32_t k = skey[idx];
    bool take = tiepath ? (k > V32 || (k == V32 && idx <= Texact))
                        : (k > ZKEY && k >= cut32);
    if (take) {
      uint32_t p = atomicAdd(&s_cnt, 1u);
      if (p < 128u)
        ck[p] = ((unsigned long long)k << 32) | (unsigned long long)(~idx);
    }
  }
  __syncthreads();
  if (tid < 128 && (uint32_t)tid >= s_cnt) ck[tid] = 0ull;
  __syncthreads();

  // bitonic sort 128 descending by (key, ~idx)
  for (int kk = 2; kk <= 128; kk <<= 1) {
    for (int j = kk >> 1; j > 0; j >>= 1) {
      if (tid < 128) {
        int ixj = tid ^ j;
        if (ixj > tid) {
          unsigned long long a = ck[tid], bb = ck[ixj];
          if ((a < bb) == ((tid & kk) == 0)) { ck[tid] = bb; ck[ixj] = a; }
        }
      }
      __syncthreads();
    }
  }

  if (tid < MAXD) {
    unsigned long long keyv = ck[tid];
    int f = (int)(~(uint32_t)(keyv & 0xFFFFFFFFull));   // flat idx = c*K + k
    int c = f / KSEL;
    float sc2 = keyinv((uint32_t)(keyv >> 32));
    const float* cb = candBox + ((size_t)b * MFLAT + f) * 4;
    float* o = out + ((size_t)b * MAXD + tid) * 6;
    o[0] = cb[0]; o[1] = cb[1]; o[2] = cb[2]; o[3] = cb[3];
    o[4] = (float)c; o[5] = sc2;
  }
}

// ---------- host ----------
extern "C" void kernel_launch(void* const* d_in, const int* in_sizes, int n_in,
                              void* d_out, int out_size, void* d_ws, size_t ws_size,
                              hipStream_t stream) {
  const float* enc = (const float*)d_in[0];      // [B,N,4]
  const float* logits = (const float*)d_in[1];   // [B,N,C]
  const float* anchors = (const float*)d_in[2];  // [N,4]
  float* out = (float*)d_out;                    // [B,100,6]
  char* ws = (char*)d_ws;

  size_t off = 0;
  float* candBox = (float*)(ws + off);   off += (size_t)B_ * C_ * KSEL * 4 * sizeof(float); // 2.30 MB
  float* candScore = (float*)(ws + off); off += (size_t)B_ * C_ * KSEL * sizeof(float);     // 0.58 MB
  uint32_t* candPacked = (uint32_t*)(ws + off);
  off += (size_t)B_ * C_ * NPAIR * sizeof(uint32_t);                                        // 0.74 MB
  uint32_t* candCount = (uint32_t*)(ws + off); off += (size_t)B_ * C_ * sizeof(uint32_t);
  off = (off + 255) & ~(size_t)255;
  uint16_t* keys16T = (uint16_t*)(ws + off);
  size_t needT = off + (size_t)B_ * C_ * NN * sizeof(uint16_t);                             // +47.2 MB
  int transposed = (ws_size >= needT) ? 1 : 0;

  if (transposed) {
    transpose_key16_kernel<<<dim3(NN / 128, B_), 256, 0, stream>>>(logits, keys16T);
    select_kernel<1><<<dim3(C_, B_), 512, 0, stream>>>(keys16T, logits, candPacked, candCount);
  } else {
    select_kernel<0><<<dim3(C_, B_), 512, 0, stream>>>(keys16T, logits, candPacked, candCount);
  }

  sort_nms_kernel<<<dim3(C_, B_), 256, 0, stream>>>(candPacked, candCount, logits,
                                                    enc, anchors, candBox, candScore);

  final_topk_kernel<<<B_, FT_NT, 0, stream>>>(candScore, candBox, out);
}